// Round 6
// baseline (102.151 us; speedup 1.0000x reference)
//
#include <hip/hip_runtime.h>

#define B_   32
#define T_   8192
#define F_   16
#define OUT_ 24
#define K1_  10
#define ND   19            // combined kernel width
#define JP   32            // padded N
#define TB   512           // timesteps per main block
#define WROWS 536          // staged window rows: [t0-18, t0+TB+1] + slack
#define H1OFF (WROWS * 8 + 8)   // hi-half LDS offset in shorts (+16B de-alias)

// ws layout (bytes):
// [0, 20480)            w2pk: bf16 packed W-frags [tbl=2][ks=10][lane=64][z=8]
// [20480, 20576)        Bc fp32[24]
// [20576, 144992)       E fp32[9][24][9][16]
#define WS_BC_OFF   20480
#define WS_E_OFF    20576

typedef short short8 __attribute__((ext_vector_type(8)));
typedef float float4v __attribute__((ext_vector_type(4)));

__device__ __forceinline__ unsigned short f2bf(float f) {
    unsigned u = __builtin_bit_cast(unsigned, f);
    unsigned r = (u + 0x7fffu + ((u >> 16) & 1u)) >> 16;  // RNE
    return (unsigned short)r;
}

__device__ __forceinline__ short8 cvt8(float4 f0, float4 f1) {
    short8 v;
    v[0] = (short)f2bf(f0.x); v[1] = (short)f2bf(f0.y);
    v[2] = (short)f2bf(f0.z); v[3] = (short)f2bf(f0.w);
    v[4] = (short)f2bf(f1.x); v[5] = (short)f2bf(f1.y);
    v[6] = (short)f2bf(f1.z); v[7] = (short)f2bf(f1.w);
    return v;
}

// stage one c-half of w1 into LDS, transposed to wl[row=k*16+i][cc] with
// XOR bank swizzle (cc ^ (row&31)); coalesced float4 global reads.
// wl[row*64 + (cc^(row&31))] == w1t[row*128 + half*64 + cc] == w1[c*160+i*10+k]
__device__ __forceinline__ void stage_w1_half(const float4* __restrict__ w4,
                                              float* __restrict__ wl,
                                              int tid, int half) {
    for (int n = 0; n < 10; ++n) {
        int f4 = half * 2560 + n * 256 + tid;
        float4 v = w4[f4];
        int f = f4 * 4;
#pragma unroll
        for (int m = 0; m < 4; ++m) {
            int ff = f + m;
            int c = ff / 160;
            int rem = ff - c * 160;
            int i = rem / 10;
            int k = rem - i * 10;
            int row = k * 16 + i;
            int cc = c - half * 64;
            float e = (m == 0) ? v.x : (m == 1) ? v.y : (m == 2) ? v.z : v.w;
            wl[row * 64 + (cc ^ (row & 31))] = e;
        }
    }
}

// ---------------- prep (single kernel; pre folded in):
// blocks 0..159: W2 waves, wid=bx*4+(tid>>6) -> j=wid/20 in [0,32), d=wid%20 in [0,20).
//   Covers ALL 10240 w2pk slots bijectively; inactive (j>=24||d>=19) waves write 0
//   -> no separate memset. w1 staged per-block in LDS (two c-half passes).
// blocks 160..165: Bc(j), wave-per-j, no LDS.
// blocks 166..651: E(t,j,tau) waves, eidx=(bx-166)*4+(tid>>6) in [0,1944);
//   same LDS staging of w1, reads wl instead of global w1t.
__global__ __launch_bounds__(256) void prep_kernel(const float* __restrict__ w1,
                                                   const float* __restrict__ b1,
                                                   const float* __restrict__ wf,
                                                   const float* __restrict__ bf,
                                                   unsigned short* __restrict__ w2pk,
                                                   float* __restrict__ bcg,
                                                   float* __restrict__ Eg) {
    int tid = threadIdx.x;
    int bx = blockIdx.x;
    int lane = tid & 63;

    __shared__ float wl[160 * 64];              // 40 KB: one c-half of w1, transposed

    if (bx < 160) {
        int wid = bx * 4 + (tid >> 6);          // 0..639
        int j = wid / 20;
        int d = wid - j * 20;                   // j 0..31, d 0..19
        bool active = (j < 24) && (d < 19);
        int klo = d - 9 > 0 ? d - 9 : 0;
        int khi = d < 9 ? d : 9;

        float p[16];
#pragma unroll
        for (int i = 0; i < 16; ++i) p[i] = 0.f;

        for (int half = 0; half < 2; ++half) {
            if (half) __syncthreads();          // drain half-0 readers before restage
            stage_w1_half((const float4*)w1, wl, tid, half);
            __syncthreads();

            if (active) {
                for (int k = klo; k <= khi; ++k) {
                    float wv = wf[j * 1280 + k * 128 + half * 64 + lane];
                    int rb = (d - k) * 16;
#pragma unroll
                    for (int i = 0; i < 16; ++i) {
                        int row = rb + i;
                        p[i] = fmaf(wv, wl[row * 64 + (lane ^ (row & 31))], p[i]);
                    }
                }
            }
        }

#pragma unroll
        for (int i = 0; i < 16; ++i) {
            p[i] += __shfl_xor(p[i], 1);
            p[i] += __shfl_xor(p[i], 2);
            p[i] += __shfl_xor(p[i], 4);
            p[i] += __shfl_xor(p[i], 8);
            p[i] += __shfl_xor(p[i], 16);
            p[i] += __shfl_xor(p[i], 32);
        }
        if (lane < 16) {
            float v = p[0];
#pragma unroll
            for (int i = 1; i < 16; ++i)
                if (lane == i) v = p[i];
            int kk = d * 16 + lane;
            int ks = kk >> 5, r = kk & 31;
            int quad = r >> 3, z = r & 7;
            int tbl = j >> 4, jj = j & 15;
            int lt = jj + quad * 16;
            w2pk[((tbl * 10 + ks) * 64 + lt) * 8 + z] = f2bf(v);
        }
    } else if (bx < 166) {
        // Bc(j): bcg[j] = bf[j] + sum_k sum_c wf[j,k,c] * b1[c]
        int j = (bx - 160) * 4 + (tid >> 6);    // 0..23
        float s0 = 0.f, s1 = 0.f;
#pragma unroll
        for (int k = 0; k < K1_; ++k) {
            s0 += wf[j * 1280 + k * 128 + lane];
            s1 += wf[j * 1280 + k * 128 + 64 + lane];
        }
        float s = s0 * b1[lane] + s1 * b1[64 + lane];
        s += __shfl_xor(s, 1);
        s += __shfl_xor(s, 2);
        s += __shfl_xor(s, 4);
        s += __shfl_xor(s, 8);
        s += __shfl_xor(s, 16);
        s += __shfl_xor(s, 32);
        if (lane == 0) bcg[j] = bf[j] + s;
    } else {
        int eidx = (bx - 166) * 4 + (tid >> 6); // 0..1943
        int t = eidx / 216;
        int rem = eidx % 216;
        int j = rem / 9, tau = rem % 9;
        float p[16];
#pragma unroll
        for (int i = 0; i < 16; ++i) p[i] = 0.f;

        for (int half = 0; half < 2; ++half) {
            if (half) __syncthreads();
            stage_w1_half((const float4*)w1, wl, tid, half);
            __syncthreads();

            for (int k = 0; k < K1_; ++k) {
                int u = t + k - 9; if (u < 0) u = 0;
                if (tau > u) continue;
                int kap = tau + 9 - u;
                float wv = wf[j * 1280 + k * 128 + half * 64 + lane];
                int rb = kap * 16;
#pragma unroll
                for (int i = 0; i < 16; ++i) {
                    int row = rb + i;
                    p[i] = fmaf(wv, wl[row * 64 + (lane ^ (row & 31))], p[i]);
                }
            }
        }

#pragma unroll
        for (int i = 0; i < 16; ++i) {
            p[i] += __shfl_xor(p[i], 1);
            p[i] += __shfl_xor(p[i], 2);
            p[i] += __shfl_xor(p[i], 4);
            p[i] += __shfl_xor(p[i], 8);
            p[i] += __shfl_xor(p[i], 16);
            p[i] += __shfl_xor(p[i], 32);
        }
        if (lane < 16) {
            float v = p[0];
#pragma unroll
            for (int i = 1; i < 16; ++i)
                if (lane == i) v = p[i];
            Eg[((t * OUT_ + j) * 9 + tau) * 16 + lane] = v;
        }
    }
}

// ---------------- main: transposed MFMA GEMM (W=A, x=B), fused fp32->bf16 LDS staging.
// grid (17, 32): x=0..15 GEMM over 512 t each; x==16 head (t<9).
// acc split into two mt-passes of 4 (reg reuse via #pragma unroll 1) to cut VGPR
// and raise occupancy; __launch_bounds__(256,3) caps allocation at 3 waves/SIMD.
__global__ __launch_bounds__(256, 3) void main_kernel(const float* __restrict__ x,
                                                   const unsigned short* __restrict__ w2pk,
                                                   const float* __restrict__ bcg,
                                                   float* __restrict__ out,
                                                   const float* __restrict__ Eg) {
    int tid = threadIdx.x;
    int b = blockIdx.y;

    if (blockIdx.x == 16) {    // head: t in [0,9)
        if (tid >= 9 * OUT_) return;
        int t = tid / OUT_, j = tid % OUT_;
        const float4* xv = (const float4*)(x + (long)b * T_ * F_);
        const float4* ev = (const float4*)(Eg + (long)tid * 144);
        float ax = 0.f, ay = 0.f, az = 0.f, aw = 0.f;
#pragma unroll
        for (int q = 0; q < 36; ++q) {
            float4 e = ev[q];
            float4 v = xv[q];
            ax = fmaf(e.x, v.x, ax);
            ay = fmaf(e.y, v.y, ay);
            az = fmaf(e.z, v.z, az);
            aw = fmaf(e.w, v.w, aw);
        }
        out[((long)b * T_ + t) * OUT_ + j] = bcg[j] + ((ax + ay) + (az + aw));
        return;
    }

    __shared__ short xls[2 * WROWS * 8 + 8];   // 17168 B: lo-half @0, hi-half @H1OFF
    int t0 = blockIdx.x * TB;

    // stage x window: global fp32 (coalesced) -> bf16 -> LDS; zero outside [0,T)
    for (int idx = tid; idx < 2 * WROWS; idx += 256) {
        int h = idx >= WROWS;
        int row = h ? idx - WROWS : idx;
        int t = t0 - 18 + row;
        short8 v = short8{0, 0, 0, 0, 0, 0, 0, 0};
        if (t >= 0 && t < T_) {
            const float4* p = (const float4*)(x + ((long)b * T_ + t) * 16 + h * 8);
            v = cvt8(p[0], p[1]);
        }
        *(short8*)(xls + h * H1OFF + row * 8) = v;
    }

    int lane = tid & 63, w = tid >> 6;
    int t = lane & 15, q = lane >> 4;
    int h = q & 1, qh = q >> 1;

    // W A-frags: read once per wave (coalesced 1KB loads, L1-hot)
    const unsigned short* pk0 = w2pk + lane * 8;          // tbl0: j = 0..15
    const unsigned short* pk1 = w2pk + 5120 + lane * 8;   // tbl1: j = 16..31
    short8 W0[10], W1[10];
#pragma unroll
    for (int ks = 0; ks < 10; ++ks) {
        W0[ks] = *(const short8*)(pk0 + ks * 512);
        W1[ks] = *(const short8*)(pk1 + ks * 512);
    }

    __syncthreads();

    const short* ap = xls + h * H1OFF + (w * 128 + t + qh) * 8;

    long outb = (long)b * T_;
    float4 bc0 = *(const float4*)(bcg + q * 4);
    float4 bc1 = (q < 2) ? *(const float4*)(bcg + 16 + q * 4) : make_float4(0.f, 0.f, 0.f, 0.f);
    bool edge = (blockIdx.x == 0);

    float4v acc[4][2];
#pragma unroll 1
    for (int pass = 0; pass < 2; ++pass) {
#pragma unroll
        for (int mt = 0; mt < 4; ++mt) {
            acc[mt][0] = float4v{0.f, 0.f, 0.f, 0.f};
            acc[mt][1] = float4v{0.f, 0.f, 0.f, 0.f};
        }

#pragma unroll
        for (int ks = 0; ks < 10; ++ks) {
#pragma unroll
            for (int mt = 0; mt < 4; ++mt) {
                short8 xf = *(const short8*)(ap + ((pass * 4 + mt) * 16 + 2 * ks) * 8);
                acc[mt][0] = __builtin_amdgcn_mfma_f32_16x16x32_bf16(W0[ks], xf, acc[mt][0], 0, 0, 0);
                acc[mt][1] = __builtin_amdgcn_mfma_f32_16x16x32_bf16(W1[ks], xf, acc[mt][1], 0, 0, 0);
            }
        }

        // epilogue: C col = t, row = j = q*4+reg (+16 for tbl1) -> float4 stores
#pragma unroll
        for (int mt = 0; mt < 4; ++mt) {
            int t_out = t0 + w * 128 + (pass * 4 + mt) * 16 + t;
            if (!edge || t_out >= 9) {        // t<9 owned by head
                float* o = out + (outb + t_out) * OUT_;
                float4 v0 = make_float4(acc[mt][0][0] + bc0.x, acc[mt][0][1] + bc0.y,
                                        acc[mt][0][2] + bc0.z, acc[mt][0][3] + bc0.w);
                *(float4*)(o + q * 4) = v0;
                if (q < 2) {
                    float4 v1 = make_float4(acc[mt][1][0] + bc1.x, acc[mt][1][1] + bc1.y,
                                            acc[mt][1][2] + bc1.z, acc[mt][1][3] + bc1.w);
                    *(float4*)(o + 16 + q * 4) = v1;
                }
            }
        }
    }
}

extern "C" void kernel_launch(void* const* d_in, const int* in_sizes, int n_in,
                              void* d_out, int out_size, void* d_ws, size_t ws_size,
                              hipStream_t stream) {
    const float* x  = (const float*)d_in[0];
    const float* w1 = (const float*)d_in[1];
    const float* b1 = (const float*)d_in[2];
    const float* wf = (const float*)d_in[3];
    const float* bf = (const float*)d_in[4];
    float* out = (float*)d_out;
    unsigned short* w2pk = (unsigned short*)d_ws;
    float* bcg = (float*)((char*)d_ws + WS_BC_OFF);
    float* Eg  = (float*)((char*)d_ws + WS_E_OFF);

    hipLaunchKernelGGL(prep_kernel, dim3(652), dim3(256), 0, stream,
                       w1, b1, wf, bf, w2pk, bcg, Eg);
    hipLaunchKernelGGL(main_kernel, dim3(17, B_), dim3(256), 0, stream,
                       x, w2pk, bcg, out, Eg);
}

// Round 7
// 91.627 us; speedup vs baseline: 1.1149x; 1.1149x over previous
//
#include <hip/hip_runtime.h>

#define B_   32
#define T_   8192
#define F_   16
#define OUT_ 24
#define K1_  10
#define ND   19            // combined kernel width
#define JP   32            // padded N
#define TB   512           // timesteps per main block
#define WROWS 536          // staged window rows: [t0-18, t0+TB+1] + slack
#define H1OFF (WROWS * 8 + 8)   // hi-half LDS offset in shorts (+16B de-alias)

// ws layout (bytes):
// [0, 20480)            w2pk: bf16 packed W-frags [tbl=2][ks=10][lane=64][z=8]
// [20480, 20576)        Bc fp32[24]
// [20576, 34400)        Q fp32[9][24][16]: head correction y[t<9]+=Q[t,j,:].x[b,0,:]
// [144992, 226912)      w1t fp32[(k*16+i)*128 + c]
#define WS_BC_OFF   20480
#define WS_Q_OFF    20576
#define WS_W1T_OFF  144992

typedef short short8 __attribute__((ext_vector_type(8)));
typedef float float4v __attribute__((ext_vector_type(4)));

__device__ __forceinline__ unsigned short f2bf(float f) {
    unsigned u = __builtin_bit_cast(unsigned, f);
    unsigned r = (u + 0x7fffu + ((u >> 16) & 1u)) >> 16;  // RNE
    return (unsigned short)r;
}

__device__ __forceinline__ short8 cvt8(float4 f0, float4 f1) {
    short8 v;
    v[0] = (short)f2bf(f0.x); v[1] = (short)f2bf(f0.y);
    v[2] = (short)f2bf(f0.z); v[3] = (short)f2bf(f0.w);
    v[4] = (short)f2bf(f1.x); v[5] = (short)f2bf(f1.y);
    v[6] = (short)f2bf(f1.z); v[7] = (short)f2bf(f1.w);
    return v;
}

// ---------------- pre (tiny): w1t transpose (blocks 0..79) + w2pk zero (80..119)
__global__ __launch_bounds__(256) void pre_kernel(const float* __restrict__ w1,
                                                  float* __restrict__ w1t,
                                                  unsigned short* __restrict__ w2pk) {
    int bx = blockIdx.x;
    int tid = threadIdx.x;
    if (bx < 80) {
        int idx = bx * 256 + tid;                // 20480 elems
        float v = w1[idx];
        int c = idx / 160;
        int rem = idx - c * 160;
        int i = rem / 10;
        int k = rem - i * 10;
        w1t[(k * 16 + i) * 128 + c] = v;
    } else {
        int idx = (bx - 80) * 256 + tid;         // 10240 uints
        ((unsigned*)w2pk)[idx] = 0;
    }
}

// ---------------- prep: wave-per-task, no barriers. grid 174 x 256.
// waves 0..455: W2(j,d); 456..479: Bc(j); 480..695: Q(t,j) head-correction table.
// Q[t,j,i] = sum_c (sum_{k<=8-t} wf[j,k,c]) * w1[c,i,9]   (h[0]-b1 = w1[:,:,9].x0)
__global__ __launch_bounds__(256) void prep_kernel(const float* __restrict__ w1t,
                                                   const float* __restrict__ b1,
                                                   const float* __restrict__ wf,
                                                   const float* __restrict__ bf,
                                                   unsigned short* __restrict__ w2pk,
                                                   float* __restrict__ bcg,
                                                   float* __restrict__ Qg) {
    int tid = threadIdx.x;
    int lane = tid & 63;
    int wid = blockIdx.x * 4 + (tid >> 6);

    if (wid < 456) {
        int j = wid / ND, d = wid % ND;
        float p[16];
#pragma unroll
        for (int i = 0; i < 16; ++i) p[i] = 0.f;
        int klo = d - 9 > 0 ? d - 9 : 0;
        int khi = d < 9 ? d : 9;
        for (int k = klo; k <= khi; ++k) {
            float w0 = wf[j * 1280 + k * 128 + lane];
            float w1v = wf[j * 1280 + k * 128 + 64 + lane];
            const float* wb = w1t + (d - k) * 16 * 128;
#pragma unroll
            for (int i = 0; i < 16; ++i)
                p[i] = fmaf(w0, wb[i * 128 + lane], fmaf(w1v, wb[i * 128 + 64 + lane], p[i]));
        }
#pragma unroll
        for (int i = 0; i < 16; ++i) {
            p[i] += __shfl_xor(p[i], 1);
            p[i] += __shfl_xor(p[i], 2);
            p[i] += __shfl_xor(p[i], 4);
            p[i] += __shfl_xor(p[i], 8);
            p[i] += __shfl_xor(p[i], 16);
            p[i] += __shfl_xor(p[i], 32);
        }
        if (lane < 16) {
            float v = p[0];
#pragma unroll
            for (int i = 1; i < 16; ++i)
                if (lane == i) v = p[i];
            int kk = d * 16 + lane;
            int ks = kk >> 5, r = kk & 31;
            int quad = r >> 3, z = r & 7;
            int tbl = j >> 4, jj = j & 15;
            int lt = jj + quad * 16;
            w2pk[((tbl * 10 + ks) * 64 + lt) * 8 + z] = f2bf(v);
        }
    } else if (wid < 480) {
        int j = wid - 456;
        float s0 = 0.f, s1 = 0.f;
#pragma unroll
        for (int k = 0; k < K1_; ++k) {
            s0 += wf[j * 1280 + k * 128 + lane];
            s1 += wf[j * 1280 + k * 128 + 64 + lane];
        }
        float s = s0 * b1[lane] + s1 * b1[64 + lane];
        s += __shfl_xor(s, 1);
        s += __shfl_xor(s, 2);
        s += __shfl_xor(s, 4);
        s += __shfl_xor(s, 8);
        s += __shfl_xor(s, 16);
        s += __shfl_xor(s, 32);
        if (lane == 0) bcg[j] = bf[j] + s;
    } else {
        int qidx = wid - 480;                 // 0..215
        int t = qidx / OUT_, j = qidx % OUT_;
        // sw[c] = sum_{k<=8-t} wf[j,k,c], split lane/lane+64
        float s0 = 0.f, s1 = 0.f;
        for (int k = 0; k <= 8 - t; ++k) {
            s0 += wf[j * 1280 + k * 128 + lane];
            s1 += wf[j * 1280 + k * 128 + 64 + lane];
        }
        const float* wb = w1t + 144 * 128;    // rows (9*16+i): w1[:, i, k1=9]
        float p[16];
#pragma unroll
        for (int i = 0; i < 16; ++i)
            p[i] = fmaf(s0, wb[i * 128 + lane], s1 * wb[i * 128 + 64 + lane]);
#pragma unroll
        for (int i = 0; i < 16; ++i) {
            p[i] += __shfl_xor(p[i], 1);
            p[i] += __shfl_xor(p[i], 2);
            p[i] += __shfl_xor(p[i], 4);
            p[i] += __shfl_xor(p[i], 8);
            p[i] += __shfl_xor(p[i], 16);
            p[i] += __shfl_xor(p[i], 32);
        }
        if (lane < 16) {
            float v = p[0];
#pragma unroll
            for (int i = 1; i < 16; ++i)
                if (lane == i) v = p[i];
            Qg[qidx * 16 + lane] = v;
        }
    }
}

// ---------------- main: transposed MFMA GEMM (W=A, x=B), fused fp32->bf16 LDS staging.
// grid (16, 32): 512 t per block. Edge block (x==0) also emits t<9 directly:
// its zero-padded staging already yields y_gemm[t<9]; add fp32 corr Q[t,j,:].x[b,0,:].
__global__ __launch_bounds__(256, 3) void main_kernel(const float* __restrict__ x,
                                                   const unsigned short* __restrict__ w2pk,
                                                   const float* __restrict__ bcg,
                                                   float* __restrict__ out,
                                                   const float* __restrict__ Qg) {
    int tid = threadIdx.x;
    int b = blockIdx.y;

    __shared__ short xls[2 * WROWS * 8 + 8];   // 17168 B: lo-half @0, hi-half @H1OFF
    int t0 = blockIdx.x * TB;

    // stage x window: global fp32 (coalesced) -> bf16 -> LDS; zero outside [0,T)
    for (int idx = tid; idx < 2 * WROWS; idx += 256) {
        int h = idx >= WROWS;
        int row = h ? idx - WROWS : idx;
        int t = t0 - 18 + row;
        short8 v = short8{0, 0, 0, 0, 0, 0, 0, 0};
        if (t >= 0 && t < T_) {
            const float4* p = (const float4*)(x + ((long)b * T_ + t) * 16 + h * 8);
            v = cvt8(p[0], p[1]);
        }
        *(short8*)(xls + h * H1OFF + row * 8) = v;
    }

    int lane = tid & 63, w = tid >> 6;
    int t = lane & 15, q = lane >> 4;
    int h = q & 1, qh = q >> 1;

    // W A-frags: read once per wave (coalesced 1KB loads, L1-hot)
    const unsigned short* pk0 = w2pk + lane * 8;          // tbl0: j = 0..15
    const unsigned short* pk1 = w2pk + 5120 + lane * 8;   // tbl1: j = 16..31
    short8 W0[10], W1[10];
#pragma unroll
    for (int ks = 0; ks < 10; ++ks) {
        W0[ks] = *(const short8*)(pk0 + ks * 512);
        W1[ks] = *(const short8*)(pk1 + ks * 512);
    }

    __syncthreads();

    const short* ap = xls + h * H1OFF + (w * 128 + t + qh) * 8;

    long outb = (long)b * T_;
    float4 bc0 = *(const float4*)(bcg + q * 4);
    float4 bc1 = (q < 2) ? *(const float4*)(bcg + 16 + q * 4) : make_float4(0.f, 0.f, 0.f, 0.f);
    bool edge = (blockIdx.x == 0);

    float4v acc[4][2];
#pragma unroll 1
    for (int pass = 0; pass < 2; ++pass) {
#pragma unroll
        for (int mt = 0; mt < 4; ++mt) {
            acc[mt][0] = float4v{0.f, 0.f, 0.f, 0.f};
            acc[mt][1] = float4v{0.f, 0.f, 0.f, 0.f};
        }

#pragma unroll
        for (int ks = 0; ks < 10; ++ks) {
#pragma unroll
            for (int mt = 0; mt < 4; ++mt) {
                short8 xf = *(const short8*)(ap + ((pass * 4 + mt) * 16 + 2 * ks) * 8);
                acc[mt][0] = __builtin_amdgcn_mfma_f32_16x16x32_bf16(W0[ks], xf, acc[mt][0], 0, 0, 0);
                acc[mt][1] = __builtin_amdgcn_mfma_f32_16x16x32_bf16(W1[ks], xf, acc[mt][1], 0, 0, 0);
            }
        }

        // epilogue: C col = t, row = j = q*4+reg (+16 for tbl1) -> float4 stores
#pragma unroll
        for (int mt = 0; mt < 4; ++mt) {
            int t_out = t0 + w * 128 + (pass * 4 + mt) * 16 + t;
            float* o = out + (outb + t_out) * OUT_;
            float4 v0 = make_float4(acc[mt][0][0] + bc0.x, acc[mt][0][1] + bc0.y,
                                    acc[mt][0][2] + bc0.z, acc[mt][0][3] + bc0.w);
            float4 v1 = make_float4(acc[mt][1][0] + bc1.x, acc[mt][1][1] + bc1.y,
                                    acc[mt][1][2] + bc1.z, acc[mt][1][3] + bc1.w);
            if (edge && t_out < 9) {   // head corr: y += Q[t_out, j, :] . x[b, 0, :]
                const float* x0 = x + (long)b * T_ * F_;
                const float* Qt = Qg + t_out * OUT_ * 16;
                float c0[4] = {0.f, 0.f, 0.f, 0.f};
#pragma unroll
                for (int r = 0; r < 4; ++r) {
                    const float* qr = Qt + (q * 4 + r) * 16;
#pragma unroll
                    for (int i = 0; i < 16; ++i) c0[r] = fmaf(qr[i], x0[i], c0[r]);
                }
                v0.x += c0[0]; v0.y += c0[1]; v0.z += c0[2]; v0.w += c0[3];
                if (q < 2) {
                    float c1[4] = {0.f, 0.f, 0.f, 0.f};
#pragma unroll
                    for (int r = 0; r < 4; ++r) {
                        const float* qr = Qt + (16 + q * 4 + r) * 16;
#pragma unroll
                        for (int i = 0; i < 16; ++i) c1[r] = fmaf(qr[i], x0[i], c1[r]);
                    }
                    v1.x += c1[0]; v1.y += c1[1]; v1.z += c1[2]; v1.w += c1[3];
                }
            }
            *(float4*)(o + q * 4) = v0;
            if (q < 2) *(float4*)(o + 16 + q * 4) = v1;
        }
    }
}

extern "C" void kernel_launch(void* const* d_in, const int* in_sizes, int n_in,
                              void* d_out, int out_size, void* d_ws, size_t ws_size,
                              hipStream_t stream) {
    const float* x  = (const float*)d_in[0];
    const float* w1 = (const float*)d_in[1];
    const float* b1 = (const float*)d_in[2];
    const float* wf = (const float*)d_in[3];
    const float* bf = (const float*)d_in[4];
    float* out = (float*)d_out;
    unsigned short* w2pk = (unsigned short*)d_ws;
    float* bcg = (float*)((char*)d_ws + WS_BC_OFF);
    float* Qg  = (float*)((char*)d_ws + WS_Q_OFF);
    float* w1t = (float*)((char*)d_ws + WS_W1T_OFF);

    hipLaunchKernelGGL(pre_kernel, dim3(120), dim3(256), 0, stream, w1, w1t, w2pk);
    hipLaunchKernelGGL(prep_kernel, dim3(174), dim3(256), 0, stream,
                       w1t, b1, wf, bf, w2pk, bcg, Qg);
    hipLaunchKernelGGL(main_kernel, dim3(16, B_), dim3(256), 0, stream,
                       x, w2pk, bcg, out, Qg);
}